// Round 5
// baseline (139.026 us; speedup 1.0000x reference)
//
#include <hip/hip_runtime.h>
#include <hip/hip_bf16.h>
#include <hip/hip_fp16.h>
#include <math.h>

#define NUM_HEADS 6
#define DH 64
#define NSEQ 1024
#define DMODEL 384
#define BBATCH 8
#define WN 147456

typedef __attribute__((ext_vector_type(8))) _Float16 half8;
typedef __attribute__((ext_vector_type(4))) _Float16 half4v;
typedef __attribute__((ext_vector_type(4))) float floatx4;

static __device__ inline half8 splat8(_Float16 v) {
  half8 r = {v, v, v, v, v, v, v, v};
  return r;
}

// load 8 consecutive f32 and convert to half8 (in-register x conversion, R13)
static __device__ inline half8 ld_cvt8(const float* __restrict__ p) {
  float4 v0 = *(const float4*)p;
  float4 v1 = *(const float4*)(p + 4);
  half8 h;
  h[0] = (_Float16)v0.x; h[1] = (_Float16)v0.y;
  h[2] = (_Float16)v0.z; h[3] = (_Float16)v0.w;
  h[4] = (_Float16)v1.x; h[5] = (_Float16)v1.y;
  h[6] = (_Float16)v1.z; h[7] = (_Float16)v1.w;
  return h;
}

// ---------------- prep: W -> fp16 (R13: x no longer converted; gemm<0>
// consumes x f32 directly with in-register cvt -- saves 18MB of prep traffic
// and shrinks this kernel 3648->576 blocks) ----------------
__global__ __launch_bounds__(256) void prep_w(
    const float* __restrict__ Wq, const float* __restrict__ Wk,
    const float* __restrict__ Wv, const float* __restrict__ Wp,
    _Float16* __restrict__ WH) {
  const int idx = blockIdx.x * 256 + threadIdx.x;  // 147456 float4 granules
  const int w = idx / 36864;
  const int rr = idx - w * 36864;
  const float* W = (w == 0) ? Wq : (w == 1) ? Wk : (w == 2) ? Wv : Wp;
  float4 v = ((const float4*)W)[rr];
  half4v h;
  h[0] = (_Float16)v.x; h[1] = (_Float16)v.y;
  h[2] = (_Float16)v.z; h[3] = (_Float16)v.w;
  ((half4v*)(WH + (size_t)w * WN))[rr] = h;
}

// ---------------- MFMA NT GEMM: C = A @ W^T, fp16, LDS-staged ----------------
// R11: LDS staging + swizzle (direct-global B was +31us, R10 lesson: lanes at
// 768B stride = 16 cache lines/load). Tile 128x96: MODE0 grid (64,12)=768
// blocks = 3.0/CU exact; MODE1 grid (64,4)=256 = 1.0/CU exact.
// R12 (MODE 1): A merged from TWO self-normalized partial attention outputs:
// A = w0*A0 + w1*A1, w0 = s0/(s0+s1) per (row, head). BK=64 == DH so each
// K-iter 'it' covers exactly head 'it' -> splat-FMA at A-load time.
// R13 (MODE 0): A loaded from x in f32, converted in-register (2x float4 +
// 8 cvt per fragment) -- VALU slack in an MFMA-dense loop; x stays
// L3-resident across the 3 z-reads.
// BK=64, 6 fully-unrolled double-buffered iters (unroll REQUIRED: ar[cur] is
// a register array; runtime-indexed it spills to scratch, R7 lesson).
template <int MODE>
__global__ __launch_bounds__(256) void gemm_f16(
    const float* __restrict__ Axf, const _Float16* __restrict__ Abf,
    const _Float16* __restrict__ WH, const float* __restrict__ lam_ptr,
    _Float16* __restrict__ qs, _Float16* __restrict__ ks,
    _Float16* __restrict__ vt, float* __restrict__ outp,
    const _Float16* __restrict__ A1p, const float* __restrict__ ps) {
  __shared__ _Float16 sB[2][6144];

  const int tid = threadIdx.x;
  const int wave = tid >> 6;
  const int lane = tid & 63;
  const int quad = lane >> 4;
  const int l16 = lane & 15;

  const int bm = blockIdx.x * 128;
  const int z = (MODE == 0) ? (blockIdx.y >> 2) : 3;
  const int bn = (MODE == 0) ? ((blockIdx.y & 3) * 96) : (blockIdx.y * 96);

  float cs = 1.0f;
  if (MODE == 0 && z == 0) cs = 0.125f / (1.0f + __expf(-lam_ptr[0]));

  const _Float16* __restrict__ Wsel = WH + (size_t)z * WN;
  // staging: granule Gd = i*256 + tid; row=Gd>>3 (0..95), src g=(Gd&7)^(row&7)
  const _Float16* srcp[3];
  int dsto[3];
#pragma unroll
  for (int i = 0; i < 3; ++i) {
    const int Gd = i * 256 + tid;
    const int row = Gd >> 3;
    const int g = (Gd & 7) ^ (row & 7);
    srcp[i] = Wsel + (size_t)(bn + row) * DMODEL + g * 8;
    dsto[i] = (i * 256 + wave * 64) * 8;  // + HW lane*16B
  }

  const float* axp[2];
  const _Float16* aptr[2];
  const _Float16* aptr1[2];
#pragma unroll
  for (int mt = 0; mt < 2; ++mt) {
    const size_t ro = (size_t)(bm + wave * 32 + mt * 16 + l16) * DMODEL + quad * 8;
    axp[mt] = (MODE == 0) ? (Axf + ro) : nullptr;
    aptr[mt] = (MODE == 1) ? (Abf + ro) : nullptr;
    aptr1[mt] = (MODE == 1) ? (A1p + ro) : nullptr;
  }

  // partial-merge weights (MODE 1): w per (m-row, head=it)
  _Float16 w0h[2][6], w1h[2][6];
  if constexpr (MODE == 1) {
#pragma unroll
    for (int mt = 0; mt < 2; ++mt) {
      const int m = bm + wave * 32 + mt * 16 + l16;
      const int b = m >> 10, q = m & (NSEQ - 1);
#pragma unroll
      for (int it = 0; it < 6; ++it) {
        const float s0 = ps[(size_t)(b * NUM_HEADS + it) * NSEQ + q];
        const float s1 = ps[(size_t)(48 * NSEQ) + (size_t)(b * NUM_HEADS + it) * NSEQ + q];
        const float w0 = s0 / (s0 + s1);
        w0h[mt][it] = (_Float16)w0;
        w1h[mt][it] = (_Float16)(1.0f - w0);
      }
    }
  }

  floatx4 acc[2][6];
#pragma unroll
  for (int i = 0; i < 2; ++i)
#pragma unroll
    for (int j = 0; j < 6; ++j) acc[i][j] = (floatx4){0.f, 0.f, 0.f, 0.f};

#pragma unroll
  for (int i = 0; i < 3; ++i)
    __builtin_amdgcn_global_load_lds(
        (const __attribute__((address_space(1))) unsigned*)srcp[i],
        (__attribute__((address_space(3))) unsigned*)(&sB[0][0] + dsto[i]), 16, 0, 0);

  half8 ar[2][2][2];
#pragma unroll
  for (int mt = 0; mt < 2; ++mt)
#pragma unroll
    for (int h = 0; h < 2; ++h) {
      if constexpr (MODE == 1) {
        half8 a0 = *(const half8*)(aptr[mt] + h * 32);
        half8 a1 = *(const half8*)(aptr1[mt] + h * 32);
        ar[0][mt][h] = a0 * splat8(w0h[mt][0]) + a1 * splat8(w1h[mt][0]);
      } else {
        ar[0][mt][h] = ld_cvt8(axp[mt] + h * 32);
      }
    }

#pragma unroll
  for (int it = 0; it < 6; ++it) {
    const int cur = it & 1, nxt = cur ^ 1;
    __syncthreads();  // DMA(it) landed; buf[nxt] readers (it-1) done
    if (it + 1 < 6) {
      const int ko = (it + 1) * 64;
#pragma unroll
      for (int i = 0; i < 3; ++i)
        __builtin_amdgcn_global_load_lds(
            (const __attribute__((address_space(1))) unsigned*)(srcp[i] + ko),
            (__attribute__((address_space(3))) unsigned*)(&sB[nxt][0] + dsto[i]),
            16, 0, 0);
#pragma unroll
      for (int mt = 0; mt < 2; ++mt)
#pragma unroll
        for (int h = 0; h < 2; ++h) {
          if constexpr (MODE == 1) {
            half8 a0 = *(const half8*)(aptr[mt] + ko + h * 32);
            half8 a1 = *(const half8*)(aptr1[mt] + ko + h * 32);
            ar[nxt][mt][h] = a0 * splat8(w0h[mt][it + 1]) + a1 * splat8(w1h[mt][it + 1]);
          } else {
            ar[nxt][mt][h] = ld_cvt8(axp[mt] + ko + h * 32);
          }
        }
    }
#pragma unroll
    for (int nt = 0; nt < 6; ++nt) {
      const int row = nt * 16 + l16;
      half8 bf0 = *(const half8*)&sB[cur][row * 64 + ((quad ^ (row & 7)) << 3)];
      half8 bf1 = *(const half8*)&sB[cur][row * 64 + (((4 + quad) ^ (row & 7)) << 3)];
      acc[0][nt] = __builtin_amdgcn_mfma_f32_16x16x32_f16(ar[cur][0][0], bf0, acc[0][nt], 0, 0, 0);
      acc[0][nt] = __builtin_amdgcn_mfma_f32_16x16x32_f16(ar[cur][0][1], bf1, acc[0][nt], 0, 0, 0);
      acc[1][nt] = __builtin_amdgcn_mfma_f32_16x16x32_f16(ar[cur][1][0], bf0, acc[1][nt], 0, 0, 0);
      acc[1][nt] = __builtin_amdgcn_mfma_f32_16x16x32_f16(ar[cur][1][1], bf1, acc[1][nt], 0, 0, 0);
    }
  }

#pragma unroll
  for (int mt = 0; mt < 2; ++mt) {
    const int m0 = bm + wave * 32 + mt * 16 + quad * 4;
    const int b = m0 >> 10;
    const int n0 = m0 & (NSEQ - 1);
#pragma unroll
    for (int nt = 0; nt < 6; ++nt) {
      const int c = bn + nt * 16 + l16;
      if constexpr (MODE == 0) {
        const int head = c >> 6;
        const int d = c & 63;
        if (z == 2) {
          half4v sv;
          sv[0] = (_Float16)acc[mt][nt][0]; sv[1] = (_Float16)acc[mt][nt][1];
          sv[2] = (_Float16)acc[mt][nt][2]; sv[3] = (_Float16)acc[mt][nt][3];
          *(half4v*)&vt[((size_t)(b * NUM_HEADS + head) * DH + d) * NSEQ + n0] = sv;
        } else {
          _Float16* tgt = z ? ks : qs;
#pragma unroll
          for (int r = 0; r < 4; ++r)
            tgt[((size_t)(b * NUM_HEADS + head) * NSEQ + n0 + r) * DH + d] =
                (_Float16)(acc[mt][nt][r] * cs);
        }
      } else {
#pragma unroll
        for (int r = 0; r < 4; ++r)
          outp[(size_t)(m0 + r) * DMODEL + c] = acc[mt][nt][r];
      }
    }
  }
}

// ---------------- LDS-shared tiled attention, fp16, split-KV ----------------
// R12: KV-split x2 (blockIdx.z = kh): each block runs 8 of 16 KV chunks;
// writes SELF-NORMALIZED partial O_kh/s_kh + partial denominator s_kh to ps;
// gemm<1> merges (no reduce kernel). Result was neutral (R4) -- attn is not
// the dominant slice; kept since it's paid for and no worse. Grid (48,16,2);
// XCD heuristic: linear id == bh (mod 8) since 48%8==0 => K/V L2-resident.
// Runtime chunk loop (full unroll regressed 38->72us, R8 lesson).
__global__ __launch_bounds__(256) void attn_tile(
    const _Float16* __restrict__ qs, const _Float16* __restrict__ ks,
    const _Float16* __restrict__ vt, _Float16* __restrict__ aoh0,
    _Float16* __restrict__ aoh1, float* __restrict__ ps,
    const float* __restrict__ lam_ptr, const float* __restrict__ lsig_ptr) {
  __shared__ _Float16 sK[2][4096];
  __shared__ _Float16 sVT[2][4096];
  __shared__ _Float16 sP[4 * 1024];

  const int tid = threadIdx.x;
  const int wave = tid >> 6;   // 0..3
  const int lane = tid & 63;
  const int quad = lane >> 4;
  const int l16 = lane & 15;
  const int l16a7 = l16 & 7;

  const int bh = blockIdx.x;
  const int qbase = blockIdx.y << 6;  // 16 q-tiles of 64 rows
  const int kh = blockIdx.z;          // KV half: chunks [kh*8, kh*8+8)
  const int CH0 = kh * 8;

  const _Float16* qb = qs + (size_t)bh * NSEQ * DH;
  const _Float16* kb = ks + (size_t)bh * NSEQ * DH;
  const _Float16* vb = vt + (size_t)bh * DH * NSEQ;

  const float lam = 1.0f / (1.0f + __expf(-lam_ptr[0]));
  const float sg = log1pf(__expf(lsig_ptr[0])) + 1e-6f;
  const float ninv2s2 = -1.0f / (2.0f * sg * sg);
  const float pscale = 1.0f - lam;

  const int la31 = lane & 31;
  const float Etv = __expf(ninv2s2 * (float)(la31 * la31));
  float Exh[2][4];
#pragma unroll
  for (int mp = 0; mp < 2; ++mp)
#pragma unroll
    for (int r = 0; r < 4; ++r) {
      const int dx = (wave & 1) * 16 + l16 - mp * 16 - quad * 4 - r;
      const int idx = dx < 0 ? -dx : dx;
      Exh[mp][r] = __int_as_float(
          __builtin_amdgcn_ds_bpermute(idx << 2, __float_as_int(Etv)));
    }
  const int qy = (qbase >> 5) + (wave >> 1);

  const int qrow = qbase + wave * 16 + l16;
  half8 aqf0 = *(const half8*)&qb[(size_t)qrow * DH + quad * 8];
  half8 aqf1 = *(const half8*)&qb[(size_t)qrow * DH + 32 + quad * 8];

  // staging: 256 threads x 2 granules per buffer (512 granules = 64 rows x 64)
  const _Float16* srcK[2];
  const _Float16* srcV[2];
  int dsto[2];
#pragma unroll
  for (int i = 0; i < 2; ++i) {
    const int G = i * 256 + tid;
    const int row = G >> 3;
    const int g = (G & 7) ^ (row & 7);
    srcK[i] = kb + (size_t)row * DH + g * 8;
    srcV[i] = vb + (size_t)row * NSEQ + g * 8;
    dsto[i] = (i * 256 + wave * 64) * 8;  // + HW lane*16B
  }

  floatx4 oacc[4];
#pragma unroll
  for (int t = 0; t < 4; ++t) oacc[t] = (floatx4){0.f, 0.f, 0.f, 0.f};
  float plsum = 0.f;

#pragma unroll
  for (int i = 0; i < 2; ++i) {
    __builtin_amdgcn_global_load_lds(
        (const __attribute__((address_space(1))) unsigned*)(srcK[i] + CH0 * 4096),
        (__attribute__((address_space(3))) unsigned*)&sK[0][dsto[i]], 16, 0, 0);
    __builtin_amdgcn_global_load_lds(
        (const __attribute__((address_space(1))) unsigned*)(srcV[i] + CH0 * 64),
        (__attribute__((address_space(3))) unsigned*)&sVT[0][dsto[i]], 16, 0, 0);
  }

  for (int ch = CH0; ch < CH0 + 8; ++ch) {
    __syncthreads();
    if (ch + 1 < CH0 + 8) {
      const int nb = (ch + 1) & 1;
#pragma unroll
      for (int i = 0; i < 2; ++i) {
        __builtin_amdgcn_global_load_lds(
            (const __attribute__((address_space(1))) unsigned*)(srcK[i] + (ch + 1) * 4096),
            (__attribute__((address_space(3))) unsigned*)&sK[nb][dsto[i]], 16, 0, 0);
        __builtin_amdgcn_global_load_lds(
            (const __attribute__((address_space(1))) unsigned*)(srcV[i] + (ch + 1) * 64),
            (__attribute__((address_space(3))) unsigned*)&sVT[nb][dsto[i]], 16, 0, 0);
      }
    }
    const int buf = ch & 1;

    half8 kf[4][2];
#pragma unroll
    for (int mt = 0; mt < 4; ++mt) {
      const int row = mt * 16 + l16;
#pragma unroll
      for (int h = 0; h < 2; ++h) {
        const int g = h * 4 + quad;
        kf[mt][h] = *(const half8*)&sK[buf][row * 64 + ((g ^ (row & 7)) << 3)];
      }
    }

    floatx4 S[4];
#pragma unroll
    for (int mt = 0; mt < 4; ++mt) {
      floatx4 c = {0.f, 0.f, 0.f, 0.f};
      c = __builtin_amdgcn_mfma_f32_16x16x32_f16(kf[mt][0], aqf0, c, 0, 0, 0);
      c = __builtin_amdgcn_mfma_f32_16x16x32_f16(kf[mt][1], aqf1, c, 0, 0, 0);
      S[mt] = c;
    }

    const float dy0 = (float)(qy - 2 * ch);
    const float dy1 = dy0 - 1.0f;
    float ey[2];
    ey[0] = pscale * __expf(ninv2s2 * dy0 * dy0);
    ey[1] = pscale * __expf(ninv2s2 * dy1 * dy1);

#pragma unroll
    for (int mt = 0; mt < 4; ++mt) {
      half4v pk;
#pragma unroll
      for (int r = 0; r < 4; ++r) {
        const float p = __expf(fmaf(ey[mt >> 1], Exh[mt & 1][r], S[mt][r]));
        plsum += p;
        pk[r] = (_Float16)p;
      }
      const int gg = mt * 4 + quad;
      const int off = wave * 1024 + l16 * 64 + (((gg >> 1) ^ l16a7) << 3) + ((gg & 1) << 2);
      *(half4v*)&sP[off] = pk;
    }

    half8 pA0 = *(const half8*)&sP[wave * 1024 + l16 * 64 + ((quad ^ l16a7) << 3)];
    half8 pA1 = *(const half8*)&sP[wave * 1024 + l16 * 64 + (((4 + quad) ^ l16a7) << 3)];

#pragma unroll
    for (int dt = 0; dt < 4; ++dt) {
      const int row = dt * 16 + l16;
      half8 vf0 = *(const half8*)&sVT[buf][row * 64 + ((quad ^ (row & 7)) << 3)];
      half8 vf1 = *(const half8*)&sVT[buf][row * 64 + (((4 + quad) ^ (row & 7)) << 3)];
      oacc[dt] = __builtin_amdgcn_mfma_f32_16x16x32_f16(pA0, vf0, oacc[dt], 0, 0, 0);
      oacc[dt] = __builtin_amdgcn_mfma_f32_16x16x32_f16(pA1, vf1, oacc[dt], 0, 0, 0);
    }
  }

  plsum += __shfl_xor(plsum, 16, 64);
  plsum += __shfl_xor(plsum, 32, 64);
  const float inv = 1.0f / plsum;
  float invr[4];
#pragma unroll
  for (int rr = 0; rr < 4; ++rr)
    invr[rr] = __int_as_float(
        __builtin_amdgcn_ds_bpermute((quad * 4 + rr) << 2, __float_as_int(inv)));

  // partial denominator for the gemm<1> merge
  if (lane < 16)
    ps[(size_t)(kh * 48 + bh) * NSEQ + qbase + wave * 16 + lane] = plsum;

  _Float16* __restrict__ aout = kh ? aoh1 : aoh0;
  const int b = bh / NUM_HEADS, head = bh % NUM_HEADS;
#pragma unroll
  for (int dt = 0; dt < 4; ++dt)
#pragma unroll
    for (int rr = 0; rr < 4; ++rr)
      aout[(size_t)(b * NSEQ + qbase + wave * 16 + quad * 4 + rr) * DMODEL +
           head * DH + dt * 16 + l16] = (_Float16)(oacc[dt][rr] * invr[rr]);
}

extern "C" void kernel_launch(void* const* d_in, const int* in_sizes, int n_in,
                              void* d_out, int out_size, void* d_ws, size_t ws_size,
                              hipStream_t stream) {
  const float* x    = (const float*)d_in[0];
  const float* Wq   = (const float*)d_in[1];
  const float* Wk   = (const float*)d_in[2];
  const float* Wv   = (const float*)d_in[3];
  const float* Wp   = (const float*)d_in[4];
  const float* lamp = (const float*)d_in[5];
  const float* lsig = (const float*)d_in[6];
  float* out = (float*)d_out;

  char* ws = (char*)d_ws;
  const size_t NE = (size_t)BBATCH * NSEQ * DMODEL;  // 3,145,728
  _Float16* aoh0 = (_Float16*)ws;    // attention output half 0
  _Float16* WH = aoh0 + NE;
  _Float16* qs = WH + 4 * (size_t)WN;
  _Float16* ks = qs + NE;
  _Float16* vt = ks + NE;
  _Float16* aoh1 = vt + NE;
  float* ps = (float*)(aoh1 + NE);   // [2][48][1024] partial denominators

  prep_w<<<576, 256, 0, stream>>>(Wq, Wk, Wv, Wp, WH);

  dim3 gq(64, 12);
  gemm_f16<0><<<gq, 256, 0, stream>>>(x, nullptr, WH, lamp, qs, ks, vt,
                                      nullptr, nullptr, nullptr);

  attn_tile<<<dim3(48, 16, 2), 256, 0, stream>>>(qs, ks, vt, aoh0, aoh1, ps,
                                                 lamp, lsig);

  dim3 gp(64, 4);
  gemm_f16<1><<<gp, 256, 0, stream>>>(nullptr, aoh0, WH, lamp, nullptr,
                                      nullptr, nullptr, out, aoh1, ps);
}

// Round 6
// 131.784 us; speedup vs baseline: 1.0550x; 1.0550x over previous
//
#include <hip/hip_runtime.h>
#include <hip/hip_bf16.h>
#include <hip/hip_fp16.h>
#include <math.h>

#define NUM_HEADS 6
#define DH 64
#define NSEQ 1024
#define DMODEL 384
#define BBATCH 8
#define WN 147456

typedef __attribute__((ext_vector_type(8))) _Float16 half8;
typedef __attribute__((ext_vector_type(4))) _Float16 half4v;
typedef __attribute__((ext_vector_type(4))) float floatx4;

static __device__ inline half8 splat8(_Float16 v) {
  half8 r = {v, v, v, v, v, v, v, v};
  return r;
}

// ---------------- prep: x, W -> fp16 ----------------
// R14: restored (R13 moved x-cvt into gemm<0>'s inner load path: 2x A bytes,
// 12x redundant cvt on the barrier critical path -> +7us. Convert ONCE here.)
__global__ __launch_bounds__(256) void prep_f16(
    const float* __restrict__ x, const float* __restrict__ Wq,
    const float* __restrict__ Wk, const float* __restrict__ Wv,
    const float* __restrict__ Wp, _Float16* __restrict__ xh,
    _Float16* __restrict__ WH) {
  const int idx = blockIdx.x * 256 + threadIdx.x;
  if (idx < 786432) {
    float4 v = ((const float4*)x)[idx];
    half4v h;
    h[0] = (_Float16)v.x; h[1] = (_Float16)v.y;
    h[2] = (_Float16)v.z; h[3] = (_Float16)v.w;
    ((half4v*)xh)[idx] = h;
  } else {
    int t = idx - 786432;
    int w = t / 36864;
    int rr = t - w * 36864;
    const float* W = (w == 0) ? Wq : (w == 1) ? Wk : (w == 2) ? Wv : Wp;
    float4 v = ((const float4*)W)[rr];
    half4v h;
    h[0] = (_Float16)v.x; h[1] = (_Float16)v.y;
    h[2] = (_Float16)v.z; h[3] = (_Float16)v.w;
    ((half4v*)(WH + (size_t)w * WN))[rr] = h;
  }
}

// ---------------- MFMA NT GEMM: C = A @ W^T, fp16, LDS-staged ----------------
// R11: LDS staging + swizzle (direct-global B was +31us, R10: lanes at 768B
// stride = 16 cache lines/load). MODE0 tile 128x96, grid (64,12)=768 blocks
// = 3.0/CU exact.
// R12 (MODE 1): A merged from TWO self-normalized partial attention outputs:
// A = w0*A0 + w1*A1, w0 = s0/(s0+s1) per (row, head). BK=64 == DH so each
// K-iter 'it' covers exactly head 'it' -> splat-FMA at A-load time.
// R14 (MODE 1): M-tile 64 (MT=1): grid (128,4)=512 blocks = 2 blocks/CU
// (was 256 = 1/CU = 1 wave/SIMD: every DMA-barrier wait fully exposed, no
// TLP). W-staging volume doubles but is L2-resident.
// BK=64, 6 fully-unrolled double-buffered iters (unroll REQUIRED: ar[cur] is
// a register array; runtime-indexed it spills to scratch, R7 lesson).
template <int MODE>
__global__ __launch_bounds__(256) void gemm_f16(
    const _Float16* __restrict__ Abf, const _Float16* __restrict__ WH,
    const float* __restrict__ lam_ptr,
    _Float16* __restrict__ qs, _Float16* __restrict__ ks,
    _Float16* __restrict__ vt, float* __restrict__ outp,
    const _Float16* __restrict__ A1p, const float* __restrict__ ps) {
  __shared__ _Float16 sB[2][6144];

  constexpr int MT = (MODE == 0) ? 2 : 1;  // 32- or 16-row wave M-tiles

  const int tid = threadIdx.x;
  const int wave = tid >> 6;
  const int lane = tid & 63;
  const int quad = lane >> 4;
  const int l16 = lane & 15;

  const int bm = blockIdx.x * (MT * 64);
  const int z = (MODE == 0) ? (blockIdx.y >> 2) : 3;
  const int bn = (MODE == 0) ? ((blockIdx.y & 3) * 96) : (blockIdx.y * 96);

  float cs = 1.0f;
  if (MODE == 0 && z == 0) cs = 0.125f / (1.0f + __expf(-lam_ptr[0]));

  const _Float16* __restrict__ Wsel = WH + (size_t)z * WN;
  // staging: granule Gd = i*256 + tid; row=Gd>>3 (0..95), src g=(Gd&7)^(row&7)
  const _Float16* srcp[3];
  int dsto[3];
#pragma unroll
  for (int i = 0; i < 3; ++i) {
    const int Gd = i * 256 + tid;
    const int row = Gd >> 3;
    const int g = (Gd & 7) ^ (row & 7);
    srcp[i] = Wsel + (size_t)(bn + row) * DMODEL + g * 8;
    dsto[i] = (i * 256 + wave * 64) * 8;  // + HW lane*16B
  }

  const _Float16* aptr[MT];
  const _Float16* aptr1[MT];
#pragma unroll
  for (int mt = 0; mt < MT; ++mt) {
    const size_t ro =
        (size_t)(bm + wave * (MT * 16) + mt * 16 + l16) * DMODEL + quad * 8;
    aptr[mt] = Abf + ro;
    aptr1[mt] = (MODE == 1) ? (A1p + ro) : nullptr;
  }

  // partial-merge weights (MODE 1): w per (m-row, head=it)
  _Float16 w0h[MT][6], w1h[MT][6];
  if constexpr (MODE == 1) {
#pragma unroll
    for (int mt = 0; mt < MT; ++mt) {
      const int m = bm + wave * (MT * 16) + mt * 16 + l16;
      const int b = m >> 10, q = m & (NSEQ - 1);
#pragma unroll
      for (int it = 0; it < 6; ++it) {
        const float s0 = ps[(size_t)(b * NUM_HEADS + it) * NSEQ + q];
        const float s1 = ps[(size_t)(48 * NSEQ) + (size_t)(b * NUM_HEADS + it) * NSEQ + q];
        const float w0 = s0 / (s0 + s1);
        w0h[mt][it] = (_Float16)w0;
        w1h[mt][it] = (_Float16)(1.0f - w0);
      }
    }
  }

  floatx4 acc[MT][6];
#pragma unroll
  for (int i = 0; i < MT; ++i)
#pragma unroll
    for (int j = 0; j < 6; ++j) acc[i][j] = (floatx4){0.f, 0.f, 0.f, 0.f};

#pragma unroll
  for (int i = 0; i < 3; ++i)
    __builtin_amdgcn_global_load_lds(
        (const __attribute__((address_space(1))) unsigned*)srcp[i],
        (__attribute__((address_space(3))) unsigned*)(&sB[0][0] + dsto[i]), 16, 0, 0);

  half8 ar[2][MT][2];
#pragma unroll
  for (int mt = 0; mt < MT; ++mt)
#pragma unroll
    for (int h = 0; h < 2; ++h) {
      half8 a0 = *(const half8*)(aptr[mt] + h * 32);
      if constexpr (MODE == 1) {
        half8 a1 = *(const half8*)(aptr1[mt] + h * 32);
        ar[0][mt][h] = a0 * splat8(w0h[mt][0]) + a1 * splat8(w1h[mt][0]);
      } else {
        ar[0][mt][h] = a0;
      }
    }

#pragma unroll
  for (int it = 0; it < 6; ++it) {
    const int cur = it & 1, nxt = cur ^ 1;
    __syncthreads();  // DMA(it) landed; buf[nxt] readers (it-1) done
    if (it + 1 < 6) {
      const int ko = (it + 1) * 64;
#pragma unroll
      for (int i = 0; i < 3; ++i)
        __builtin_amdgcn_global_load_lds(
            (const __attribute__((address_space(1))) unsigned*)(srcp[i] + ko),
            (__attribute__((address_space(3))) unsigned*)(&sB[nxt][0] + dsto[i]),
            16, 0, 0);
#pragma unroll
      for (int mt = 0; mt < MT; ++mt)
#pragma unroll
        for (int h = 0; h < 2; ++h) {
          half8 a0 = *(const half8*)(aptr[mt] + ko + h * 32);
          if constexpr (MODE == 1) {
            half8 a1 = *(const half8*)(aptr1[mt] + ko + h * 32);
            ar[nxt][mt][h] = a0 * splat8(w0h[mt][it + 1]) + a1 * splat8(w1h[mt][it + 1]);
          } else {
            ar[nxt][mt][h] = a0;
          }
        }
    }
#pragma unroll
    for (int nt = 0; nt < 6; ++nt) {
      const int row = nt * 16 + l16;
      half8 bf0 = *(const half8*)&sB[cur][row * 64 + ((quad ^ (row & 7)) << 3)];
      half8 bf1 = *(const half8*)&sB[cur][row * 64 + (((4 + quad) ^ (row & 7)) << 3)];
#pragma unroll
      for (int mt = 0; mt < MT; ++mt) {
        acc[mt][nt] = __builtin_amdgcn_mfma_f32_16x16x32_f16(ar[cur][mt][0], bf0, acc[mt][nt], 0, 0, 0);
        acc[mt][nt] = __builtin_amdgcn_mfma_f32_16x16x32_f16(ar[cur][mt][1], bf1, acc[mt][nt], 0, 0, 0);
      }
    }
  }

#pragma unroll
  for (int mt = 0; mt < MT; ++mt) {
    const int m0 = bm + wave * (MT * 16) + mt * 16 + quad * 4;
    const int b = m0 >> 10;
    const int n0 = m0 & (NSEQ - 1);
#pragma unroll
    for (int nt = 0; nt < 6; ++nt) {
      const int c = bn + nt * 16 + l16;
      if constexpr (MODE == 0) {
        const int head = c >> 6;
        const int d = c & 63;
        if (z == 2) {
          half4v sv;
          sv[0] = (_Float16)acc[mt][nt][0]; sv[1] = (_Float16)acc[mt][nt][1];
          sv[2] = (_Float16)acc[mt][nt][2]; sv[3] = (_Float16)acc[mt][nt][3];
          *(half4v*)&vt[((size_t)(b * NUM_HEADS + head) * DH + d) * NSEQ + n0] = sv;
        } else {
          _Float16* tgt = z ? ks : qs;
#pragma unroll
          for (int r = 0; r < 4; ++r)
            tgt[((size_t)(b * NUM_HEADS + head) * NSEQ + n0 + r) * DH + d] =
                (_Float16)(acc[mt][nt][r] * cs);
        }
      } else {
#pragma unroll
        for (int r = 0; r < 4; ++r)
          outp[(size_t)(m0 + r) * DMODEL + c] = acc[mt][nt][r];
      }
    }
  }
}

// ---------------- LDS-shared tiled attention, fp16, split-KV ----------------
// R12: KV-split x2 (blockIdx.z = kh): each block runs 8 of 16 KV chunks;
// writes SELF-NORMALIZED partial O_kh/s_kh + partial denominator s_kh to ps;
// gemm<1> merges (no reduce kernel). Neutral (R4) but no worse; kept.
// Grid (48,16,2); XCD heuristic: linear id == bh (mod 8) since 48%8==0 =>
// K/V L2-resident. Runtime chunk loop (full unroll regressed 38->72us, R8).
__global__ __launch_bounds__(256) void attn_tile(
    const _Float16* __restrict__ qs, const _Float16* __restrict__ ks,
    const _Float16* __restrict__ vt, _Float16* __restrict__ aoh0,
    _Float16* __restrict__ aoh1, float* __restrict__ ps,
    const float* __restrict__ lam_ptr, const float* __restrict__ lsig_ptr) {
  __shared__ _Float16 sK[2][4096];
  __shared__ _Float16 sVT[2][4096];
  __shared__ _Float16 sP[4 * 1024];

  const int tid = threadIdx.x;
  const int wave = tid >> 6;   // 0..3
  const int lane = tid & 63;
  const int quad = lane >> 4;
  const int l16 = lane & 15;
  const int l16a7 = l16 & 7;

  const int bh = blockIdx.x;
  const int qbase = blockIdx.y << 6;  // 16 q-tiles of 64 rows
  const int kh = blockIdx.z;          // KV half: chunks [kh*8, kh*8+8)
  const int CH0 = kh * 8;

  const _Float16* qb = qs + (size_t)bh * NSEQ * DH;
  const _Float16* kb = ks + (size_t)bh * NSEQ * DH;
  const _Float16* vb = vt + (size_t)bh * DH * NSEQ;

  const float lam = 1.0f / (1.0f + __expf(-lam_ptr[0]));
  const float sg = log1pf(__expf(lsig_ptr[0])) + 1e-6f;
  const float ninv2s2 = -1.0f / (2.0f * sg * sg);
  const float pscale = 1.0f - lam;

  const int la31 = lane & 31;
  const float Etv = __expf(ninv2s2 * (float)(la31 * la31));
  float Exh[2][4];
#pragma unroll
  for (int mp = 0; mp < 2; ++mp)
#pragma unroll
    for (int r = 0; r < 4; ++r) {
      const int dx = (wave & 1) * 16 + l16 - mp * 16 - quad * 4 - r;
      const int idx = dx < 0 ? -dx : dx;
      Exh[mp][r] = __int_as_float(
          __builtin_amdgcn_ds_bpermute(idx << 2, __float_as_int(Etv)));
    }
  const int qy = (qbase >> 5) + (wave >> 1);

  const int qrow = qbase + wave * 16 + l16;
  half8 aqf0 = *(const half8*)&qb[(size_t)qrow * DH + quad * 8];
  half8 aqf1 = *(const half8*)&qb[(size_t)qrow * DH + 32 + quad * 8];

  // staging: 256 threads x 2 granules per buffer (512 granules = 64 rows x 64)
  const _Float16* srcK[2];
  const _Float16* srcV[2];
  int dsto[2];
#pragma unroll
  for (int i = 0; i < 2; ++i) {
    const int G = i * 256 + tid;
    const int row = G >> 3;
    const int g = (G & 7) ^ (row & 7);
    srcK[i] = kb + (size_t)row * DH + g * 8;
    srcV[i] = vb + (size_t)row * NSEQ + g * 8;
    dsto[i] = (i * 256 + wave * 64) * 8;  // + HW lane*16B
  }

  floatx4 oacc[4];
#pragma unroll
  for (int t = 0; t < 4; ++t) oacc[t] = (floatx4){0.f, 0.f, 0.f, 0.f};
  float plsum = 0.f;

#pragma unroll
  for (int i = 0; i < 2; ++i) {
    __builtin_amdgcn_global_load_lds(
        (const __attribute__((address_space(1))) unsigned*)(srcK[i] + CH0 * 4096),
        (__attribute__((address_space(3))) unsigned*)&sK[0][dsto[i]], 16, 0, 0);
    __builtin_amdgcn_global_load_lds(
        (const __attribute__((address_space(1))) unsigned*)(srcV[i] + CH0 * 64),
        (__attribute__((address_space(3))) unsigned*)&sVT[0][dsto[i]], 16, 0, 0);
  }

  for (int ch = CH0; ch < CH0 + 8; ++ch) {
    __syncthreads();
    if (ch + 1 < CH0 + 8) {
      const int nb = (ch + 1) & 1;
#pragma unroll
      for (int i = 0; i < 2; ++i) {
        __builtin_amdgcn_global_load_lds(
            (const __attribute__((address_space(1))) unsigned*)(srcK[i] + (ch + 1) * 4096),
            (__attribute__((address_space(3))) unsigned*)&sK[nb][dsto[i]], 16, 0, 0);
        __builtin_amdgcn_global_load_lds(
            (const __attribute__((address_space(1))) unsigned*)(srcV[i] + (ch + 1) * 64),
            (__attribute__((address_space(3))) unsigned*)&sVT[nb][dsto[i]], 16, 0, 0);
      }
    }
    const int buf = ch & 1;

    half8 kf[4][2];
#pragma unroll
    for (int mt = 0; mt < 4; ++mt) {
      const int row = mt * 16 + l16;
#pragma unroll
      for (int h = 0; h < 2; ++h) {
        const int g = h * 4 + quad;
        kf[mt][h] = *(const half8*)&sK[buf][row * 64 + ((g ^ (row & 7)) << 3)];
      }
    }

    floatx4 S[4];
#pragma unroll
    for (int mt = 0; mt < 4; ++mt) {
      floatx4 c = {0.f, 0.f, 0.f, 0.f};
      c = __builtin_amdgcn_mfma_f32_16x16x32_f16(kf[mt][0], aqf0, c, 0, 0, 0);
      c = __builtin_amdgcn_mfma_f32_16x16x32_f16(kf[mt][1], aqf1, c, 0, 0, 0);
      S[mt] = c;
    }

    const float dy0 = (float)(qy - 2 * ch);
    const float dy1 = dy0 - 1.0f;
    float ey[2];
    ey[0] = pscale * __expf(ninv2s2 * dy0 * dy0);
    ey[1] = pscale * __expf(ninv2s2 * dy1 * dy1);

#pragma unroll
    for (int mt = 0; mt < 4; ++mt) {
      half4v pk;
#pragma unroll
      for (int r = 0; r < 4; ++r) {
        const float p = __expf(fmaf(ey[mt >> 1], Exh[mt & 1][r], S[mt][r]));
        plsum += p;
        pk[r] = (_Float16)p;
      }
      const int gg = mt * 4 + quad;
      const int off = wave * 1024 + l16 * 64 + (((gg >> 1) ^ l16a7) << 3) + ((gg & 1) << 2);
      *(half4v*)&sP[off] = pk;
    }

    half8 pA0 = *(const half8*)&sP[wave * 1024 + l16 * 64 + ((quad ^ l16a7) << 3)];
    half8 pA1 = *(const half8*)&sP[wave * 1024 + l16 * 64 + (((4 + quad) ^ l16a7) << 3)];

#pragma unroll
    for (int dt = 0; dt < 4; ++dt) {
      const int row = dt * 16 + l16;
      half8 vf0 = *(const half8*)&sVT[buf][row * 64 + ((quad ^ (row & 7)) << 3)];
      half8 vf1 = *(const half8*)&sVT[buf][row * 64 + (((4 + quad) ^ (row & 7)) << 3)];
      oacc[dt] = __builtin_amdgcn_mfma_f32_16x16x32_f16(pA0, vf0, oacc[dt], 0, 0, 0);
      oacc[dt] = __builtin_amdgcn_mfma_f32_16x16x32_f16(pA1, vf1, oacc[dt], 0, 0, 0);
    }
  }

  plsum += __shfl_xor(plsum, 16, 64);
  plsum += __shfl_xor(plsum, 32, 64);
  const float inv = 1.0f / plsum;
  float invr[4];
#pragma unroll
  for (int rr = 0; rr < 4; ++rr)
    invr[rr] = __int_as_float(
        __builtin_amdgcn_ds_bpermute((quad * 4 + rr) << 2, __float_as_int(inv)));

  // partial denominator for the gemm<1> merge
  if (lane < 16)
    ps[(size_t)(kh * 48 + bh) * NSEQ + qbase + wave * 16 + lane] = plsum;

  _Float16* __restrict__ aout = kh ? aoh1 : aoh0;
  const int b = bh / NUM_HEADS, head = bh % NUM_HEADS;
#pragma unroll
  for (int dt = 0; dt < 4; ++dt)
#pragma unroll
    for (int rr = 0; rr < 4; ++rr)
      aout[(size_t)(b * NSEQ + qbase + wave * 16 + quad * 4 + rr) * DMODEL +
           head * DH + dt * 16 + l16] = (_Float16)(oacc[dt][rr] * invr[rr]);
}

extern "C" void kernel_launch(void* const* d_in, const int* in_sizes, int n_in,
                              void* d_out, int out_size, void* d_ws, size_t ws_size,
                              hipStream_t stream) {
  const float* x    = (const float*)d_in[0];
  const float* Wq   = (const float*)d_in[1];
  const float* Wk   = (const float*)d_in[2];
  const float* Wv   = (const float*)d_in[3];
  const float* Wp   = (const float*)d_in[4];
  const float* lamp = (const float*)d_in[5];
  const float* lsig = (const float*)d_in[6];
  float* out = (float*)d_out;

  char* ws = (char*)d_ws;
  const size_t NE = (size_t)BBATCH * NSEQ * DMODEL;  // 3,145,728
  _Float16* xh = (_Float16*)ws;      // later reused as attention output 0
  _Float16* WH = xh + NE;
  _Float16* qs = WH + 4 * (size_t)WN;
  _Float16* ks = qs + NE;
  _Float16* vt = ks + NE;
  _Float16* aoh0 = xh;               // alias: x no longer needed after QKV
  _Float16* aoh1 = vt + NE;
  float* ps = (float*)(aoh1 + NE);   // [2][48][1024] partial denominators

  prep_f16<<<3648, 256, 0, stream>>>(x, Wq, Wk, Wv, Wp, xh, WH);

  dim3 gq(64, 12);
  gemm_f16<0><<<gq, 256, 0, stream>>>(xh, WH, lamp, qs, ks, vt, nullptr,
                                      nullptr, nullptr);

  attn_tile<<<dim3(48, 16, 2), 256, 0, stream>>>(qs, ks, vt, aoh0, aoh1, ps,
                                                 lamp, lsig);

  dim3 gp(128, 4);
  gemm_f16<1><<<gp, 256, 0, stream>>>(aoh0, WH, lamp, nullptr, nullptr,
                                      nullptr, out, aoh1, ps);
}